// Round 19
// baseline (122.375 us; speedup 1.0000x reference)
//
#include <hip/hip_runtime.h>

constexpr int Bn = 8, Cn = 3, Hn = 720, Wn = 1280;
constexpr int HW = Hn * Wn;                    // 921600 px per image
constexpr long long NTOT = (long long)Bn * Cn * HW;

constexpr int BLK  = 256;
constexpr int TH   = 16, TW = 64;              // output tile 16x64 = 1024 px
constexpr int TCOL = Wn / TW;                  // 20 tile-cols
constexpr int TPI  = (Hn / TH) * TCOL;         // 900 tiles per image
constexpr int NWG  = 8 * TPI;                  // 7200 blocks; bid&7 = image/XCD
constexpr int PXT  = (TH * TW) / BLK;          // 4 px per thread
constexpr int WR   = 24;                       // window rows: Y-4 .. Y+19 (border-replicated)
constexpr int WC   = 84;                       // window cols: XS-4 .. XS+79
constexpr int F4W  = WC / 4;                   // 21 f4 per window row
constexpr int F4P  = WR * F4W;                 // 504 f4 slots per plane
constexpr int NF4  = 2 * F4P;                  // 1008 slots per channel (L+R)
constexpr int PSE  = 2048;                     // bf16 plane stride (elements)
constexpr int BUFE = 2 * PSE;                  // 4096 bf16 = 8 KB per channel buffer

typedef float f4 __attribute__((ext_vector_type(4)));

__device__ __forceinline__ float bf(unsigned short h) {
    return __uint_as_float((unsigned)h << 16);
}

// 4 f32 -> 4 bf16 (RNE) -> one 8B LDS write
__device__ __forceinline__ void put8(unsigned short* dst, f4 v) {
    unsigned r0, r1;
    asm("v_cvt_pk_bf16_f32 %0, %1, %2" : "=v"(r0) : "v"(v[0]), "v"(v[1]));
    asm("v_cvt_pk_bf16_f32 %0, %1, %2" : "=v"(r1) : "v"(v[2]), "v"(v[3]));
    uint2 u; u.x = r0; u.y = r1;
    *reinterpret_cast<uint2*>(dst) = u;
}

__global__ __launch_bounds__(256) void warp_loss_kernel(
        const float* __restrict__ L, const float* __restrict__ R,
        const float* __restrict__ Flm, const float* __restrict__ Frm,
        const float* __restrict__ G, double* __restrict__ accum) {
    // XCD k (= bid%8) owns image k; t = tile id, row-major sweep (halo in L2).
    // bf16 double-buffered windows: 16.2 KB LDS -> 8 blocks/CU = 32 waves,
    // channel pipeline keeps loads outstanding while sampling (T14).
    const int b    = blockIdx.x & 7;
    const int t    = blockIdx.x >> 3;          // [0, 900)
    const int trow = t / TCOL;
    const int tcol = t - trow * TCOL;
    const int Y    = trow * TH;
    const int XS   = tcol * TW;
    const int tid  = (int)threadIdx.x;

    const float* __restrict__ Lb = L + (size_t)b * Cn * HW;
    const float* __restrict__ Rb = R + (size_t)b * Cn * HW;
    const float* __restrict__ Gb = G + (size_t)b * Cn * HW;
    const float* __restrict__ fl = Flm + (size_t)b * 2 * HW;  // [0,HW)=x, [HW,2HW)=y
    const float* __restrict__ fr = Frm + (size_t)b * 2 * HW;

    __shared__ unsigned short win[2][BUFE];    // 16 KB: two channel buffers
    __shared__ float wsum[4];

    // ---- staging slot geometry (channel-invariant). slot s -> plane pl,
    //      window (wr, c4); 16 tail threads clamp to last slot (dup write,
    //      same src -> same value, benign). ----
    int soff[4], dstE[4];
    #pragma unroll
    for (int k = 0; k < 4; ++k) {
        const int s  = min(k * BLK + tid, NF4 - 1);
        const int pl = (s >= F4P) ? 1 : 0;
        const int f  = s - pl * F4P;
        const int wr = f / F4W;
        const int c4 = f - wr * F4W;
        const int ys = min(max(Y - 4 + wr, 0), Hn - 1);
        const int xw = min(max(XS - 4 + c4 * 4, 0), Wn - 4);  // 16B-aligned, in-bounds
        soff[k] = ys * Wn + xw;
        dstE[k] = pl * PSE + wr * WC + c4 * 4; // element idx; *2B is 8B-aligned
    }

    // ---- prologue: issue channel-0 staging loads FIRST (in flight under
    //      the tap preamble), then taps, then cvt+write, barrier ----
    f4 s0, s1, s2, s3;
    s0 = *reinterpret_cast<const f4*>((dstE[0] >= PSE ? Rb : Lb) + soff[0]);
    s1 = *reinterpret_cast<const f4*>((dstE[1] >= PSE ? Rb : Lb) + soff[1]);
    s2 = *reinterpret_cast<const f4*>((dstE[2] >= PSE ? Rb : Lb) + soff[2]);
    s3 = *reinterpret_cast<const f4*>((dstE[3] >= PSE ? Rb : Lb) + soff[3]);

    // ---- per-px tap state (channel-invariant), coalesced flow loads ----
    int   aL[PXT], aR[PXT];
    float lwx[PXT], lwy[PXT], rwx[PXT], rwy[PXT];
    #pragma unroll
    for (int k = 0; k < PXT; ++k) {
        const int i = k * BLK + tid;
        const int r = i >> 6, cm = i & 63;
        const int y = Y + r, x = XS + cm;
        const int p = y * Wn + x;
        {
            const float fx = fminf(fmaxf(fl[p],      -4.0f), 3.99951171875f);
            const float fy = fminf(fmaxf(fl[HW + p], -4.0f), 3.99951171875f);
            const float xc = fminf(fmaxf((float)x + fx, 0.f), (float)(Wn - 1));
            const float yc = fminf(fmaxf((float)y + fy, 0.f), (float)(Hn - 1));
            const float x0f = floorf(xc), y0f = floorf(yc);
            lwx[k] = xc - x0f;  lwy[k] = yc - y0f;
            aL[k] = ((int)y0f - (Y - 4)) * WC + ((int)x0f - (XS - 4));
        }
        {
            const float fx = fminf(fmaxf(fr[p],      -4.0f), 3.99951171875f);
            const float fy = fminf(fmaxf(fr[HW + p], -4.0f), 3.99951171875f);
            const float xc = fminf(fmaxf((float)x + fx, 0.f), (float)(Wn - 1));
            const float yc = fminf(fmaxf((float)y + fy, 0.f), (float)(Hn - 1));
            const float x0f = floorf(xc), y0f = floorf(yc);
            rwx[k] = xc - x0f;  rwy[k] = yc - y0f;
            aR[k] = PSE + ((int)y0f - (Y - 4)) * WC + ((int)x0f - (XS - 4));
        }
    }

    put8(&win[0][dstE[0]], s0);
    put8(&win[0][dstE[1]], s1);
    put8(&win[0][dstE[2]], s2);
    put8(&win[0][dstE[3]], s3);
    __syncthreads();

    float local = 0.f;

    for (int c = 0; c < Cn; ++c) {
        // (1) issue next channel's staging loads (latency hides under sampling)
        if (c < Cn - 1) {
            const float* __restrict__ Lc = Lb + (size_t)(c + 1) * HW;
            const float* __restrict__ Rc = Rb + (size_t)(c + 1) * HW;
            s0 = *reinterpret_cast<const f4*>((dstE[0] >= PSE ? Rc : Lc) + soff[0]);
            s1 = *reinterpret_cast<const f4*>((dstE[1] >= PSE ? Rc : Lc) + soff[1]);
            s2 = *reinterpret_cast<const f4*>((dstE[2] >= PSE ? Rc : Lc) + soff[2]);
            s3 = *reinterpret_cast<const f4*>((dstE[3] >= PSE ? Rc : Lc) + soff[3]);
        }

        // (2) gt loads for this channel
        float g[PXT];
        #pragma unroll
        for (int k = 0; k < PXT; ++k) {
            const int i = k * BLK + tid;
            const int p = (Y + (i >> 6)) * Wn + XS + (i & 63);
            g[k] = Gb[(size_t)c * HW + p];
        }

        // (3) sample channel c from win[c&1]
        const unsigned short* __restrict__ w = win[c & 1];
        #pragma unroll
        for (int k = 0; k < PXT; ++k) {
            const int a = aL[k];
            const float v00 = bf(w[a]),      v01 = bf(w[a + 1]);
            const float v10 = bf(w[a + WC]), v11 = bf(w[a + WC + 1]);
            float top = fmaf(lwx[k], v01 - v00, v00);
            float bot = fmaf(lwx[k], v11 - v10, v10);
            const float sL = fmaf(lwy[k], bot - top, top);
            const int a2 = aR[k];
            const float u00 = bf(w[a2]),      u01 = bf(w[a2 + 1]);
            const float u10 = bf(w[a2 + WC]), u11 = bf(w[a2 + WC + 1]);
            top = fmaf(rwx[k], u01 - u00, u00);
            bot = fmaf(rwx[k], u11 - u10, u10);
            const float sR = fmaf(rwy[k], bot - top, top);
            local += fabsf(sL - g[k]) + fabsf(sR - g[k]);
        }

        // (4) write next channel's window into the other buffer; one barrier
        if (c < Cn - 1) {
            unsigned short* __restrict__ wd = win[(c + 1) & 1];
            put8(&wd[dstE[0]], s0);
            put8(&wd[dstE[1]], s1);
            put8(&wd[dstE[2]], s2);
            put8(&wd[dstE[3]], s3);
            __syncthreads();
        }
    }

    // wave(64) shuffle reduce -> LDS cross-wave -> one f64 atomic per block
    #pragma unroll
    for (int off = 32; off > 0; off >>= 1)
        local += __shfl_down(local, off, 64);

    const int lane = tid & 63;
    const int wid  = tid >> 6;
    if (lane == 0) wsum[wid] = local;
    __syncthreads();
    if (tid == 0) {
        const float s = wsum[0] + wsum[1] + wsum[2] + wsum[3];
        atomicAdd(accum, (double)s);
    }
}

__global__ void finalize_kernel(const double* __restrict__ accum,
                                float* __restrict__ out) {
    out[0] = (float)(accum[0] / (double)NTOT);
}

extern "C" void kernel_launch(void* const* d_in, const int* in_sizes, int n_in,
                              void* d_out, int out_size, void* d_ws, size_t ws_size,
                              hipStream_t stream) {
    const float* L   = (const float*)d_in[0];
    const float* R   = (const float*)d_in[1];
    const float* flm = (const float*)d_in[2];
    const float* frm = (const float*)d_in[3];
    const float* gt  = (const float*)d_in[4];
    double* accum = (double*)d_ws;

    (void)hipMemsetAsync(accum, 0, sizeof(double), stream);
    warp_loss_kernel<<<NWG, BLK, 0, stream>>>(L, R, flm, frm, gt, accum);
    finalize_kernel<<<1, 1, 0, stream>>>(accum, (float*)d_out);
}